// Round 12
// baseline (679.017 us; speedup 1.0000x reference)
//
#include <hip/hip_runtime.h>
#include <hip/hip_bf16.h>

#define NROWS 100000
#define G1_NRB 1563   // ceil(100000/64)
#define G2_NRB 2084   // ceil(100000/48)
#define G1_NT (G1_NRB * 11)
#define G2_NT (G2_NRB * 11)

typedef __attribute__((ext_vector_type(8))) short bf16x8;
typedef __attribute__((ext_vector_type(4))) float f32x4;
typedef float f32x4a8 __attribute__((ext_vector_type(4), aligned(8)));

__device__ __forceinline__ short f2b(float f) {
  __hip_bfloat16 h = __float2bfloat16(f);
  short s;
  __builtin_memcpy(&s, &h, sizeof(s));
  return s;
}

__device__ __forceinline__ float sigf(float x) { return 1.f / (1.f + __expf(-x)); }
__device__ __forceinline__ float tanh_f(float x) { return 1.f - 2.f / (__expf(2.f * x) + 1.f); }

__device__ __forceinline__ float4 ld4a8(const float* __restrict__ p) {
  f32x4a8 v = *(const f32x4a8*)p;
  return make_float4(v[0], v[1], v[2], v[3]);
}

__device__ __forceinline__ float4 u2f4(uint4 u) {
  float4 f;
  __builtin_memcpy(&f, &u, 16);
  return f;
}

__device__ __forceinline__ bf16x8 raw2bf8(float4 lo) {
  bf16x8 r;
  __builtin_memcpy(&r, &lo, 16);
  return r;
}

__device__ __forceinline__ bf16x8 cvt2bf8(float4 lo, float4 hi) {
  bf16x8 r;
  r[0] = f2b(lo.x); r[1] = f2b(lo.y); r[2] = f2b(lo.z); r[3] = f2b(lo.w);
  r[4] = f2b(hi.x); r[5] = f2b(hi.y); r[6] = f2b(hi.z); r[7] = f2b(hi.w);
  return r;
}

// ---------------- weight packing: per-(kt,mtile,gate) lane-contiguous 1KB frags ---
// B1r: frag = (kt*11+mt)*4+gate; elem lane*8+b; k = kt*32+(lane>>4)*8+b,
//      m = mt*16+(lane&15). X1 K-rows: e|tag|tagp|h|bias(568)|0 (576 pad).
// B2r: frag = (kt*11+mt)*5+gate; X2 K-rows REORDERED:
//      h1(0:168)|tag(168:218)|tagp(218:268)|k(268:436)|bias(436)|0 (448 pad).
//      Uh on h1, Wt on tag, Wtp on tagp, Uk on k (gates 0-3 only).
#define NB1R (18 * 11 * 4 * 512)
#define NB2R (14 * 11 * 5 * 512)

__global__ void pack_weights(const float* __restrict__ We_l, const float* __restrict__ Wt_l,
                             const float* __restrict__ Wtp_l, const float* __restrict__ Uh_l,
                             const float* __restrict__ b_l,
                             const float* __restrict__ Wt_n, const float* __restrict__ Wtp_n,
                             const float* __restrict__ Uh_n, const float* __restrict__ Uk_n,
                             const float* __restrict__ b_n,
                             unsigned short* __restrict__ B1r, unsigned short* __restrict__ B2r) {
  int idx = blockIdx.x * blockDim.x + threadIdx.x;
  if (idx < NB1R) {
    int b = idx & 7, lane = (idx >> 3) & 63, fr = idx >> 9;
    int gate = fr & 3, tmp = fr >> 2;
    int mt = tmp % 11, kt = tmp / 11;
    int k = kt * 32 + ((lane >> 4) << 3) + b;
    int m = mt * 16 + (lane & 15);
    float v = 0.f;
    if (m < 168) {
      int col = gate * 168 + m;
      if (k < 300)       v = We_l[k * 672 + col];
      else if (k < 350)  v = Wt_l[(k - 300) * 672 + col];
      else if (k < 400)  v = Wtp_l[(k - 350) * 672 + col];
      else if (k < 568)  v = Uh_l[(k - 400) * 672 + col];
      else if (k == 568) v = b_l[col];
    }
    B1r[idx] = (unsigned short)f2b(v);
  } else if (idx < NB1R + NB2R) {
    int j = idx - NB1R;
    int b = j & 7, lane = (j >> 3) & 63, fr = j >> 9;
    int gate = fr % 5, tmp = fr / 5;
    int mt = tmp % 11, kt = tmp / 11;
    int k = kt * 32 + ((lane >> 4) << 3) + b;
    int m = mt * 16 + (lane & 15);
    float v = 0.f;
    if (m < 168) {
      int col = gate * 168 + m;
      if (k < 168)       v = Uh_n[k * 840 + col];
      else if (k < 218)  v = Wt_n[(k - 168) * 840 + col];
      else if (k < 268)  v = Wtp_n[(k - 218) * 840 + col];
      else if (k < 436)  v = (gate < 4) ? Uk_n[(k - 268) * 672 + gate * 168 + m] : 0.f;
      else if (k == 436) v = b_n[col];
    }
    B2r[j] = (unsigned short)f2b(v);
  }
}

// ---------------- GEMM1: leaf cell, barrier-free register streaming -------------
// Wave-task = (rb64, mtile): 64 rows x 16 m x 4 gates. acc[4][4] f32x4 = 64 VGPR.
__global__ __launch_bounds__(256, 3) void gemm1_kernel(
    const float* __restrict__ e, const float* __restrict__ tg, const float* __restrict__ tp,
    const float* __restrict__ hp, const float* __restrict__ cprev,
    const unsigned short* __restrict__ B1r, unsigned short* __restrict__ c1buf,
    unsigned short* __restrict__ h1buf) {
  const int tid = threadIdx.x, wave = tid >> 6, ln = tid & 63;
  const int wid = blockIdx.x * 4 + wave;
  if (wid >= G1_NT) return;
  const int rb = wid / 11, mt = wid - rb * 11;
  const int c = ln & 15, rg = ln >> 4;
  const int k0base = rg << 3;

  int row[4];
#pragma unroll
  for (int rt = 0; rt < 4; ++rt) {
    int r = rb * 64 + rt * 16 + c;
    row[rt] = r < NROWS ? r : NROWS - 1;
  }
  const char* bptr = (const char*)B1r + (size_t)mt * 4096 + (size_t)ln * 16;

  // X1 = [e(0:300)|tag(300:350)|tagp(350:400)|h(400:568)|bias(568)|0]
  auto loadA = [&](int kt, int rt, float4& lo, float4& hi) {
    const int k0 = kt * 32 + k0base;
    const int r = row[rt];
    if (k0 + 8 <= 300) {
      const float* p = e + r * 300 + k0;
      lo = *(const float4*)p; hi = *(const float4*)(p + 4);
    } else if (k0 == 296) {
      lo = *(const float4*)(e + r * 300 + 296);
      hi = ld4a8(tg + r * 50);
    } else if (k0 >= 304 && k0 + 8 <= 350) {
      const float* p = tg + r * 50 + (k0 - 300);
      lo = ld4a8(p); hi = ld4a8(p + 4);
    } else if (k0 == 344) {
      lo = ld4a8(tg + r * 50 + 44);
      hi = make_float4(tg[r * 50 + 48], tg[r * 50 + 49], tp[r * 50 + 0], tp[r * 50 + 1]);
    } else if (k0 >= 352 && k0 + 8 <= 400) {
      const float* p = tp + r * 50 + (k0 - 350);
      lo = ld4a8(p); hi = ld4a8(p + 4);
    } else if (k0 >= 400 && k0 + 8 <= 568) {
      const float* p = hp + r * 168 + (k0 - 400);
      lo = *(const float4*)p; hi = *(const float4*)(p + 4);
    } else {  // k0 == 568: bias column
      lo = make_float4(1.f, 0.f, 0.f, 0.f);
      hi = make_float4(0.f, 0.f, 0.f, 0.f);
    }
  };
  auto loadB = [&](int kt, int g) -> bf16x8 {
    return *(const bf16x8*)(bptr + (size_t)kt * 45056 + (size_t)g * 1024);
  };

  f32x4 acc[4][4];
  const f32x4 z4 = {0.f, 0.f, 0.f, 0.f};
#pragma unroll
  for (int rt = 0; rt < 4; ++rt)
#pragma unroll
    for (int g = 0; g < 4; ++g) acc[rt][g] = z4;

  float4 alo[4], ahi[4];
  bf16x8 Bb[2][4];
#pragma unroll
  for (int rt = 0; rt < 4; ++rt) loadA(0, rt, alo[rt], ahi[rt]);
#pragma unroll
  for (int g = 0; g < 4; ++g) Bb[0][g] = loadB(0, g);

#pragma unroll
  for (int kt = 0; kt < 18; ++kt) {
    bf16x8 af[4];
#pragma unroll
    for (int rt = 0; rt < 4; ++rt) af[rt] = cvt2bf8(alo[rt], ahi[rt]);
    if (kt + 1 < 18) {
#pragma unroll
      for (int rt = 0; rt < 4; ++rt) loadA(kt + 1, rt, alo[rt], ahi[rt]);
#pragma unroll
      for (int g = 0; g < 4; ++g) Bb[(kt + 1) & 1][g] = loadB(kt + 1, g);
    }
#pragma unroll
    for (int rt = 0; rt < 4; ++rt)
#pragma unroll
      for (int g = 0; g < 4; ++g)
        acc[rt][g] = __builtin_amdgcn_mfma_f32_16x16x32_bf16(af[rt], Bb[kt & 1][g], acc[rt][g], 0, 0, 0);
  }

  const int m = mt * 16 + c;
  if (m < 168) {
#pragma unroll
    for (int rt = 0; rt < 4; ++rt) {
#pragma unroll
      for (int reg = 0; reg < 4; ++reg) {
        const int r = rb * 64 + rt * 16 + (rg << 2) + reg;
        if (r >= NROWS) continue;
        const float iv = acc[rt][0][reg];
        const float ov = acc[rt][1][reg];
        const float fv = acc[rt][2][reg];
        const float uv = acc[rt][3][reg];
        const int off = r * 168 + m;
        const float cp = cprev[off];
        const float c1 = sigf(iv) * tanh_f(uv) + sigf(fv) * cp;
        const float h1 = sigf(ov) * tanh_f(c1);
        c1buf[off] = (unsigned short)f2b(c1);
        h1buf[off] = (unsigned short)f2b(h1);
      }
    }
  }
}

// ---------------- GEMM2: node cell, barrier-free register streaming -------------
// Wave-task = (rb48, mtile): 48 rows x 16 m x 5 gates. acc[3][5] f32x4 = 60 VGPR.
__global__ __launch_bounds__(256, 3) void gemm2_kernel(
    const float* __restrict__ tg, const float* __restrict__ tp, const float* __restrict__ kk,
    const float* __restrict__ q, const unsigned short* __restrict__ B2r,
    const unsigned short* __restrict__ c1buf, const unsigned short* __restrict__ h1buf,
    float* __restrict__ out) {
  const int tid = threadIdx.x, wave = tid >> 6, ln = tid & 63;
  const int wid = blockIdx.x * 4 + wave;
  if (wid >= G2_NT) return;
  const int rb = wid / 11, mt = wid - rb * 11;
  const int c = ln & 15, rg = ln >> 4;
  const int k0base = rg << 3;

  int row[3];
#pragma unroll
  for (int rt = 0; rt < 3; ++rt) {
    int r = rb * 48 + rt * 16 + c;
    row[rt] = r < NROWS ? r : NROWS - 1;
  }
  const char* bptr = (const char*)B2r + (size_t)mt * 5120 + (size_t)ln * 16;

  // X2 = [h1(0:168)|tag(168:218)|tagp(218:268)|k(268:436)|bias(436)|0]
  // h1 region loads raw bf16 (16B in lo); others f32 pairs.
  auto loadA = [&](int kt, int rt, float4& lo, float4& hi) {
    const int k0 = kt * 32 + k0base;
    const int r = row[rt];
    if (k0 + 8 <= 168) {
      uint4 u = *(const uint4*)(h1buf + r * 168 + k0);
      lo = u2f4(u);
      hi = make_float4(0.f, 0.f, 0.f, 0.f);
    } else if (k0 >= 168 && k0 + 8 <= 216) {
      const float* p = tg + r * 50 + (k0 - 168);
      lo = ld4a8(p); hi = ld4a8(p + 4);
    } else if (k0 == 216) {
      lo = make_float4(tg[r * 50 + 48], tg[r * 50 + 49], tp[r * 50 + 0], tp[r * 50 + 1]);
      hi = ld4a8(tp + r * 50 + 2);
    } else if (k0 >= 224 && k0 + 8 <= 264) {
      const float* p = tp + r * 50 + (k0 - 218);
      lo = ld4a8(p); hi = ld4a8(p + 4);
    } else if (k0 == 264) {
      lo = ld4a8(tp + r * 50 + 46);
      hi = *(const float4*)(kk + r * 168);
    } else if (k0 >= 272 && k0 + 8 <= 436) {
      const float* p = kk + r * 168 + (k0 - 268);
      lo = *(const float4*)p; hi = *(const float4*)(p + 4);
    } else if (k0 == 432) {
      lo = *(const float4*)(kk + r * 168 + 164);
      hi = make_float4(1.f, 0.f, 0.f, 0.f);
    } else {  // k0 == 440: zero pad
      lo = make_float4(0.f, 0.f, 0.f, 0.f);
      hi = make_float4(0.f, 0.f, 0.f, 0.f);
    }
  };
  auto loadB = [&](int kt, int g) -> bf16x8 {
    return *(const bf16x8*)(bptr + (size_t)kt * 56320 + (size_t)g * 1024);
  };

  f32x4 acc[3][5];
  const f32x4 z4 = {0.f, 0.f, 0.f, 0.f};
#pragma unroll
  for (int rt = 0; rt < 3; ++rt)
#pragma unroll
    for (int g = 0; g < 5; ++g) acc[rt][g] = z4;

  float4 alo[3], ahi[3];
  bf16x8 Bb[2][5];
#pragma unroll
  for (int rt = 0; rt < 3; ++rt) loadA(0, rt, alo[rt], ahi[rt]);
#pragma unroll
  for (int g = 0; g < 5; ++g) Bb[0][g] = loadB(0, g);

#pragma unroll
  for (int kt = 0; kt < 14; ++kt) {
    const int k0 = kt * 32 + k0base;
    const bool ish1 = (k0 + 8 <= 168);  // same classification as loadA
    bf16x8 af[3];
#pragma unroll
    for (int rt = 0; rt < 3; ++rt)
      af[rt] = ish1 ? raw2bf8(alo[rt]) : cvt2bf8(alo[rt], ahi[rt]);
    if (kt + 1 < 14) {
#pragma unroll
      for (int rt = 0; rt < 3; ++rt) loadA(kt + 1, rt, alo[rt], ahi[rt]);
#pragma unroll
      for (int g = 0; g < 5; ++g) Bb[(kt + 1) & 1][g] = loadB(kt + 1, g);
    }
#pragma unroll
    for (int rt = 0; rt < 3; ++rt)
#pragma unroll
      for (int g = 0; g < 5; ++g)
        acc[rt][g] = __builtin_amdgcn_mfma_f32_16x16x32_bf16(af[rt], Bb[kt & 1][g], acc[rt][g], 0, 0, 0);
  }

  const int m = mt * 16 + c;
  if (m < 168) {
#pragma unroll
    for (int rt = 0; rt < 3; ++rt) {
#pragma unroll
      for (int reg = 0; reg < 4; ++reg) {
        const int r = rb * 48 + rt * 16 + (rg << 2) + reg;
        if (r >= NROWS) continue;
        const float i2 = acc[rt][0][reg];
        const float o2 = acc[rt][1][reg];
        const float fl2 = acc[rt][2][reg];
        const float fd2 = acc[rt][3][reg];
        const float u2 = acc[rt][4][reg];
        const int off = r * 168 + m;
        const float c1 = __bfloat162float(*(const __hip_bfloat16*)&c1buf[off]);
        const float qv = q[off];
        const float c2 = sigf(i2) * tanh_f(u2) + sigf(fd2) * qv + sigf(fl2) * c1;
        const float h2 = sigf(o2) * tanh_f(c2);
        out[r * 336 + m] = h2;
        out[r * 336 + 168 + m] = c2;
      }
    }
  }
}

extern "C" void kernel_launch(void* const* d_in, const int* in_sizes, int n_in,
                              void* d_out, int out_size, void* d_ws, size_t ws_size,
                              hipStream_t stream) {
  const float* e     = (const float*)d_in[0];
  const float* tag   = (const float*)d_in[1];
  const float* tagp  = (const float*)d_in[2];
  const float* hprev = (const float*)d_in[3];
  const float* cprev = (const float*)d_in[4];
  const float* kk    = (const float*)d_in[5];
  const float* q     = (const float*)d_in[6];
  const float* We_l  = (const float*)d_in[7];
  const float* Wt_l  = (const float*)d_in[8];
  const float* Wtp_l = (const float*)d_in[9];
  const float* Uh_l  = (const float*)d_in[10];
  const float* b_l   = (const float*)d_in[11];
  const float* Wt_n  = (const float*)d_in[12];
  const float* Wtp_n = (const float*)d_in[13];
  const float* Uh_n  = (const float*)d_in[14];
  const float* Uk_n  = (const float*)d_in[15];
  const float* b_n   = (const float*)d_in[16];
  float* out = (float*)d_out;

  char* ws = (char*)d_ws;
  unsigned short* B1r = (unsigned short*)ws;                              // 811,008 B
  unsigned short* B2r = (unsigned short*)(ws + (1 << 20));                // 788,480 B
  unsigned short* c1buf = (unsigned short*)(ws + (2 << 20));              // 33,600,000 B
  unsigned short* h1buf = (unsigned short*)(ws + (2 << 20) + 33600000);   // 33,600,000 B

  const int NB = NB1R + NB2R;
  pack_weights<<<(NB + 255) / 256, 256, 0, stream>>>(We_l, Wt_l, Wtp_l, Uh_l, b_l,
                                                     Wt_n, Wtp_n, Uh_n, Uk_n, b_n, B1r, B2r);

  gemm1_kernel<<<(G1_NT + 3) / 4, 256, 0, stream>>>(e, tag, tagp, hprev, cprev,
                                                    B1r, c1buf, h1buf);
  gemm2_kernel<<<(G2_NT + 3) / 4, 256, 0, stream>>>(tag, tagp, kk, q,
                                                    B2r, c1buf, h1buf, out);
}